// Round 4
// baseline (183.523 us; speedup 1.0000x reference)
//
#include <hip/hip_runtime.h>
#include <hip/hip_bf16.h>

#define N_NODES 200000
#define KDIM 27
#define C_IN 32
#define C_OUT 32

// software pipeline depths (fully unrolled -> static indexing, no scratch)
#define PF 4            // fragment prefetch distance (stages)
#define IPD 4           // extra index prefetch distance ahead of fragment issue
#define IB (PF + IPD)   // index ring size

typedef __bf16 bf16x8 __attribute__((ext_vector_type(8)));
typedef float floatx4 __attribute__((ext_vector_type(4)));
typedef float float4_t __attribute__((ext_vector_type(4)));

__device__ inline bf16x8 zero_bf16x8() {
    bf16x8 z;
#pragma unroll
    for (int i = 0; i < 8; ++i) z[i] = (__bf16)0.0f;
    return z;
}

// Kernel 1: convert fp32 data -> bf16 (8 elems/thread), plus zero the sentinel
// node at data_bf[N_NODES] (used for branchless invalid-neighbor gathers).
__global__ __launch_bounds__(256) void convert_data_kernel(
    const float* __restrict__ src, __bf16* __restrict__ dst) {
    int i = blockIdx.x * 256 + threadIdx.x;   // 800000 threads, exact
    const float4_t* s = (const float4_t*)src;
    float4_t v0 = __builtin_nontemporal_load(&s[2 * i]);      // fp32 src is read-once
    float4_t v1 = __builtin_nontemporal_load(&s[2 * i + 1]);
    bf16x8 o;
    o[0] = (__bf16)v0[0]; o[1] = (__bf16)v0[1];
    o[2] = (__bf16)v0[2]; o[3] = (__bf16)v0[3];
    o[4] = (__bf16)v1[0]; o[5] = (__bf16)v1[1];
    o[6] = (__bf16)v1[2]; o[7] = (__bf16)v1[3];
    ((bf16x8*)dst)[i] = o;
    if (blockIdx.x == 0 && threadIdx.x < 4) {
        // sentinel node (index N_NODES): 32 bf16 zeros = 4 x bf16x8
        ((bf16x8*)dst)[N_NODES * 4 + threadIdx.x] = zero_bf16x8();
    }
}

// Kernel 2: pack weights [K][C_IN][C_OUT] fp32 -> bf16 B-fragment layout:
// wp[((kk*2 + t)*64 + lane)*8 + j] = w[kk][ (lane>>4)*8 + j ][ t*16 + (lane&15) ]
__global__ __launch_bounds__(256) void pack_weights_kernel(
    const float* __restrict__ w, __bf16* __restrict__ wp) {
    int id = blockIdx.x * 256 + threadIdx.x;   // 27648 threads, exact (108 blocks)
    int j = id & 7;
    int l = (id >> 3) & 63;
    int t = (id >> 9) & 1;
    int kk = id >> 10;
    int c = ((l >> 4) << 3) + j;
    int o = t * 16 + (l & 15);
    wp[id] = (__bf16)w[(kk * C_IN + c) * C_OUT + o];
}

// Kernel 3: main gather-GEMM. One wave handles 32 nodes x 32 outputs.
// A-fragment (16x16x32 bf16): A[m = lane&15][k = (lane>>4)*8 + j]
// C/D: col = lane&15, row = (lane>>4)*4 + reg
//
// Pipeline per stage kk (fully unrolled, all loads unconditional):
//   MFMA on stage kk fragments (issued PF stages ago)
//   issue A/B fragment loads for stage kk+PF (indices loaded IB stages ago)
//   issue index loads for stage kk+IB
//
// __launch_bounds__(256, 3): scheduler targets 3 waves/EU (~168 VGPR cap) so
// the depth-4 ring (~130 live VGPRs) is allocatable; bare (256) made the
// compiler sink loads into their consumers (60 VGPRs, depth-1 pipeline,
// one L3 round-trip per tap — round-1 post-mortem). No sched_barrier this
// round: rounds 2-3 (which added it) never reached the GPU; single-variable
// experiment vs round 1.
__global__ __launch_bounds__(256, 3) void octconv_main_kernel(
    const int* __restrict__ neigh, const __bf16* __restrict__ data_bf,
    const __bf16* __restrict__ wpack, float* __restrict__ out) {
    const int tid  = threadIdx.x;
    const int wave = tid >> 6;
    const int lane = tid & 63;
    const int node_base = (blockIdx.x * 4 + wave) * 32;
    const int r16  = lane & 15;
    const int half = lane >> 4;
    const int cb   = half << 3;          // channel base for A fragment
    const int m0   = node_base + r16;
    const int m1   = m0 + 16;
    // clamp row index for always-valid index loads (stores remain guarded)
    const int sm0 = (m0 < N_NODES) ? m0 : (N_NODES - 1);
    const int sm1 = (m1 < N_NODES) ? m1 : (N_NODES - 1);
    const int* __restrict__ nrow0 = neigh + sm0 * KDIM;
    const int* __restrict__ nrow1 = neigh + sm1 * KDIM;
    const __bf16* __restrict__ dch = data_bf + cb;   // per-lane channel offset base
    const bf16x8* __restrict__ wp  = (const bf16x8*)wpack;

    floatx4 acc00 = {0.f, 0.f, 0.f, 0.f};
    floatx4 acc01 = {0.f, 0.f, 0.f, 0.f};
    floatx4 acc10 = {0.f, 0.f, 0.f, 0.f};
    floatx4 acc11 = {0.f, 0.f, 0.f, 0.f};

    int i0buf[IB], i1buf[IB];                  // index ring
    bf16x8 a0b[PF], a1b[PF], b0b[PF], b1b[PF]; // fragment rings

    // prologue: index loads for stages 0..IB-1 (all independent)
#pragma unroll
    for (int t = 0; t < IB; ++t) {
        i0buf[t] = __builtin_nontemporal_load(&nrow0[t]);
        i1buf[t] = __builtin_nontemporal_load(&nrow1[t]);
    }
    // prologue: fragment loads for stages 0..PF-1 (branchless sentinel gather)
#pragma unroll
    for (int t = 0; t < PF; ++t) {
        unsigned u0 = (unsigned)i0buf[t]; if (u0 > (unsigned)N_NODES) u0 = N_NODES;
        unsigned u1 = (unsigned)i1buf[t]; if (u1 > (unsigned)N_NODES) u1 = N_NODES;
        a0b[t] = *(const bf16x8*)(dch + ((size_t)u0 << 5));
        a1b[t] = *(const bf16x8*)(dch + ((size_t)u1 << 5));
        b0b[t] = wp[(t * 2 + 0) * 64 + lane];
        b1b[t] = wp[(t * 2 + 1) * 64 + lane];
    }

#pragma unroll
    for (int kk = 0; kk < KDIM; ++kk) {
        const int s = kk & (PF - 1);
        acc00 = __builtin_amdgcn_mfma_f32_16x16x32_bf16(a0b[s], b0b[s], acc00, 0, 0, 0);
        acc01 = __builtin_amdgcn_mfma_f32_16x16x32_bf16(a0b[s], b1b[s], acc01, 0, 0, 0);
        acc10 = __builtin_amdgcn_mfma_f32_16x16x32_bf16(a1b[s], b0b[s], acc10, 0, 0, 0);
        acc11 = __builtin_amdgcn_mfma_f32_16x16x32_bf16(a1b[s], b1b[s], acc11, 0, 0, 0);

        if (kk + PF < KDIM) {
            const int t = kk + PF;           // stage to issue; slot t%PF == s
            unsigned u0 = (unsigned)i0buf[t & (IB - 1)]; if (u0 > (unsigned)N_NODES) u0 = N_NODES;
            unsigned u1 = (unsigned)i1buf[t & (IB - 1)]; if (u1 > (unsigned)N_NODES) u1 = N_NODES;
            a0b[s] = *(const bf16x8*)(dch + ((size_t)u0 << 5));
            a1b[s] = *(const bf16x8*)(dch + ((size_t)u1 << 5));
            b0b[s] = wp[(t * 2 + 0) * 64 + lane];
            b1b[s] = wp[(t * 2 + 1) * 64 + lane];
        }
        if (kk + IB < KDIM) {
            i0buf[kk & (IB - 1)] = __builtin_nontemporal_load(&nrow0[kk + IB]);
            i1buf[kk & (IB - 1)] = __builtin_nontemporal_load(&nrow1[kk + IB]);
        }
    }

#pragma unroll
    for (int r = 0; r < 4; ++r) {
        int row = half * 4 + r;
        int n0 = node_base + row;
        int n1 = n0 + 16;
        if (n0 < N_NODES) {
            __builtin_nontemporal_store(acc00[r], &out[n0 * C_OUT + r16]);
            __builtin_nontemporal_store(acc01[r], &out[n0 * C_OUT + 16 + r16]);
        }
        if (n1 < N_NODES) {
            __builtin_nontemporal_store(acc10[r], &out[n1 * C_OUT + r16]);
            __builtin_nontemporal_store(acc11[r], &out[n1 * C_OUT + 16 + r16]);
        }
    }
}

extern "C" void kernel_launch(void* const* d_in, const int* in_sizes, int n_in,
                              void* d_out, int out_size, void* d_ws, size_t ws_size,
                              hipStream_t stream) {
    const float* data    = (const float*)d_in[0];   // [N, C_IN] fp32
    const float* weights = (const float*)d_in[1];   // [K, C_IN, C_OUT] fp32
    const int*   neigh   = (const int*)d_in[2];     // [N, K] int32
    float*       out     = (float*)d_out;           // [N, C_OUT] fp32

    // workspace: data_bf = (N+1) nodes (incl. zero sentinel), then wpack
    __bf16* data_bf = (__bf16*)d_ws;
    __bf16* wpack   = (__bf16*)((char*)d_ws + (size_t)(N_NODES + 1) * C_IN * sizeof(__bf16));

    // 1) data fp32 -> bf16 (+ sentinel zero-fill)
    hipLaunchKernelGGL(convert_data_kernel, dim3((N_NODES * C_IN / 8 + 255) / 256),
                       dim3(256), 0, stream, data, data_bf);
    // 2) weights fp32 -> bf16 B-fragment pack
    hipLaunchKernelGGL(pack_weights_kernel, dim3((KDIM * C_IN * C_OUT + 255) / 256),
                       dim3(256), 0, stream, weights, wpack);
    // 3) gather + MFMA GEMM; 128 nodes per block
    int blocks = (N_NODES + 127) / 128;
    hipLaunchKernelGGL(octconv_main_kernel, dim3(blocks), dim3(256), 0, stream,
                       neigh, data_bf, wpack, out);
}

// Round 5
// 170.495 us; speedup vs baseline: 1.0764x; 1.0764x over previous
//
#include <hip/hip_runtime.h>
#include <hip/hip_bf16.h>

#define N_NODES 200000
#define KDIM 27
#define C_IN 32
#define C_OUT 32

// pipeline geometry (hard-coded wait table below assumes PF=4, IB=8, KDIM=27)
#define PF 4            // fragment prefetch distance (stages)
#define IB 8            // index prefetch distance (stages)

typedef __bf16 bf16x8 __attribute__((ext_vector_type(8)));
typedef float floatx4 __attribute__((ext_vector_type(4)));
typedef float float4_t __attribute__((ext_vector_type(4)));

__device__ inline bf16x8 zero_bf16x8() {
    bf16x8 z;
#pragma unroll
    for (int i = 0; i < 8; ++i) z[i] = (__bf16)0.0f;
    return z;
}

// ---------------- Kernel 1: fp32 -> bf16 convert (+ zero sentinel node) ----
__global__ __launch_bounds__(256) void convert_data_kernel(
    const float* __restrict__ src, __bf16* __restrict__ dst) {
    int i = blockIdx.x * 256 + threadIdx.x;   // 800000 threads, exact
    const float4_t* s = (const float4_t*)src;
    float4_t v0 = __builtin_nontemporal_load(&s[2 * i]);
    float4_t v1 = __builtin_nontemporal_load(&s[2 * i + 1]);
    bf16x8 o;
    o[0] = (__bf16)v0[0]; o[1] = (__bf16)v0[1];
    o[2] = (__bf16)v0[2]; o[3] = (__bf16)v0[3];
    o[4] = (__bf16)v1[0]; o[5] = (__bf16)v1[1];
    o[6] = (__bf16)v1[2]; o[7] = (__bf16)v1[3];
    ((bf16x8*)dst)[i] = o;
    if (blockIdx.x == 0 && threadIdx.x < 4) {
        ((bf16x8*)dst)[N_NODES * 4 + threadIdx.x] = zero_bf16x8();
    }
}

// ---------------- Kernel 2: weight pack to B-fragment layout ---------------
// wp[((kk*2 + t)*64 + lane)*8 + j] = w[kk][ (lane>>4)*8 + j ][ t*16 + (lane&15) ]
__global__ __launch_bounds__(256) void pack_weights_kernel(
    const float* __restrict__ w, __bf16* __restrict__ wp) {
    int id = blockIdx.x * 256 + threadIdx.x;   // 27648 threads, exact
    int j = id & 7;
    int l = (id >> 3) & 63;
    int t = (id >> 9) & 1;
    int kk = id >> 10;
    int c = ((l >> 4) << 3) + j;
    int o = t * 16 + (l & 15);
    wp[id] = (__bf16)w[(kk * C_IN + c) * C_OUT + o];
}

// ---------------- Kernel 3: asm-pipelined gather-GEMM ----------------------
// Rounds 1/4 proved the compiler sinks compiler-tracked loads into their
// consumers at any __launch_bounds__ (VGPR 60 -> 32, depth-1 pipeline, one
// L3 round-trip per tap). So: ALL loop VMEM is inline-asm volatile (issue
// order fixed, registers force-live), with manual counted s_waitcnt vmcnt(N)
// (never 0 in steady state) + sched_barrier(0) per rule: MFMA consuming
// asm-loaded regs must not hoist above the wait.

__device__ __forceinline__ void load_frag16(bf16x8& dst, const __bf16* addr) {
    asm volatile("global_load_dwordx4 %0, %1, off" : "=v"(dst) : "v"(addr));
}
template<int BYTEOFF>
__device__ __forceinline__ void load_idx(int& dst, const int* base) {
    asm volatile("global_load_dword %0, %1, off offset:%2"
                 : "=v"(dst) : "v"(base), "n"(BYTEOFF));
}

// Wait count at top of stage j: force completion of frag(j) and (if needed)
// idx(j+PF), leaving newer prefetches in flight. Steady state: queue holds
// [frag(j),idx(j+4)] ... [frag(j+3),idx(j+7)] = 24 ops; all but newest 18
// completes frag(j)+idx(j+4). Tail: exact counts as issues stop.
constexpr int wtop(int j) {
    if (j <= 19) return 18;
    if (j == 20) return 16;
    if (j == 21) return 14;
    if (j == 22 || j == 23) return 12;
    if (j == 24) return 8;
    if (j == 25) return 4;
    return 0;
}

struct PipeState {
    bf16x8 a0[PF], a1[PF], b0[PF], b1[PF];
    int i0[IB], i1[IB];
    floatx4 acc00, acc01, acc10, acc11;
    const __bf16* dch;      // data_bf + per-lane channel base
    const __bf16* wlane;    // wpack + lane*8 elements
    const int* nrow0;
    const int* nrow1;
};

template<int J>
__device__ __forceinline__ void stage(PipeState& st) {
    asm volatile("s_waitcnt vmcnt(%0)" :: "n"(wtop(J)) : "memory");
    __builtin_amdgcn_sched_barrier(0);
    constexpr int s = J % PF;
    st.acc00 = __builtin_amdgcn_mfma_f32_16x16x32_bf16(st.a0[s], st.b0[s], st.acc00, 0, 0, 0);
    st.acc01 = __builtin_amdgcn_mfma_f32_16x16x32_bf16(st.a0[s], st.b1[s], st.acc01, 0, 0, 0);
    st.acc10 = __builtin_amdgcn_mfma_f32_16x16x32_bf16(st.a1[s], st.b0[s], st.acc10, 0, 0, 0);
    st.acc11 = __builtin_amdgcn_mfma_f32_16x16x32_bf16(st.a1[s], st.b1[s], st.acc11, 0, 0, 0);
    if constexpr (J + PF < KDIM) {
        constexpr int t = J + PF;
        unsigned u0 = (unsigned)st.i0[t % IB]; if (u0 > (unsigned)N_NODES) u0 = N_NODES;
        unsigned u1 = (unsigned)st.i1[t % IB]; if (u1 > (unsigned)N_NODES) u1 = N_NODES;
        load_frag16(st.a0[s], st.dch + ((size_t)u0 << 5));
        load_frag16(st.a1[s], st.dch + ((size_t)u1 << 5));
        load_frag16(st.b0[s], st.wlane + t * 1024);
        load_frag16(st.b1[s], st.wlane + t * 1024 + 512);
        if constexpr (J + IB < KDIM) {
            load_idx<4 * (J + IB)>(st.i0[(J + IB) % IB], st.nrow0);
            load_idx<4 * (J + IB)>(st.i1[(J + IB) % IB], st.nrow1);
        }
    }
}

template<int J>
__device__ __forceinline__ void run_stages(PipeState& st) {
    if constexpr (J < KDIM) {
        stage<J>(st);
        run_stages<J + 1>(st);
    }
}

template<int T>
__device__ __forceinline__ void prologue_block(PipeState& st) {
    unsigned u0 = (unsigned)st.i0[T]; if (u0 > (unsigned)N_NODES) u0 = N_NODES;
    unsigned u1 = (unsigned)st.i1[T]; if (u1 > (unsigned)N_NODES) u1 = N_NODES;
    load_frag16(st.a0[T], st.dch + ((size_t)u0 << 5));
    load_frag16(st.a1[T], st.dch + ((size_t)u1 << 5));
    load_frag16(st.b0[T], st.wlane + T * 1024);
    load_frag16(st.b1[T], st.wlane + T * 1024 + 512);
    load_idx<4 * (T + PF)>(st.i0[T + PF], st.nrow0);
    load_idx<4 * (T + PF)>(st.i1[T + PF], st.nrow1);
}

__global__ __launch_bounds__(256, 3) void octconv_main_kernel(
    const int* __restrict__ neigh, const __bf16* __restrict__ data_bf,
    const __bf16* __restrict__ wpack, float* __restrict__ out) {
    const int tid  = threadIdx.x;
    const int wave = tid >> 6;
    const int lane = tid & 63;
    const int node_base = (blockIdx.x * 4 + wave) * 32;
    const int r16  = lane & 15;
    const int half = lane >> 4;
    const int cb   = half << 3;
    const int m0   = node_base + r16;
    const int m1   = m0 + 16;
    const int sm0 = (m0 < N_NODES) ? m0 : (N_NODES - 1);
    const int sm1 = (m1 < N_NODES) ? m1 : (N_NODES - 1);

    PipeState st;
    st.dch   = data_bf + cb;
    st.wlane = wpack + (size_t)lane * 8;
    st.nrow0 = neigh + sm0 * KDIM;
    st.nrow1 = neigh + sm1 * KDIM;
    st.acc00 = floatx4{0.f, 0.f, 0.f, 0.f};
    st.acc01 = floatx4{0.f, 0.f, 0.f, 0.f};
    st.acc10 = floatx4{0.f, 0.f, 0.f, 0.f};
    st.acc11 = floatx4{0.f, 0.f, 0.f, 0.f};

    // prologue: idx(0..3), drain once, then interleaved frag(0..3)+idx(4..7)
    // establishing the exact steady-state queue [frag(t),idx(t+4)] x4.
    load_idx<0>(st.i0[0], st.nrow0);  load_idx<0>(st.i1[0], st.nrow1);
    load_idx<4>(st.i0[1], st.nrow0);  load_idx<4>(st.i1[1], st.nrow1);
    load_idx<8>(st.i0[2], st.nrow0);  load_idx<8>(st.i1[2], st.nrow1);
    load_idx<12>(st.i0[3], st.nrow0); load_idx<12>(st.i1[3], st.nrow1);
    asm volatile("s_waitcnt vmcnt(0)" ::: "memory");
    __builtin_amdgcn_sched_barrier(0);
    prologue_block<0>(st);
    prologue_block<1>(st);
    prologue_block<2>(st);
    prologue_block<3>(st);

    run_stages<0>(st);

#pragma unroll
    for (int r = 0; r < 4; ++r) {
        int row = half * 4 + r;
        int n0 = node_base + row;
        int n1 = n0 + 16;
        if (n0 < N_NODES) {
            __builtin_nontemporal_store(st.acc00[r], &out[n0 * C_OUT + r16]);
            __builtin_nontemporal_store(st.acc01[r], &out[n0 * C_OUT + 16 + r16]);
        }
        if (n1 < N_NODES) {
            __builtin_nontemporal_store(st.acc10[r], &out[n1 * C_OUT + r16]);
            __builtin_nontemporal_store(st.acc11[r], &out[n1 * C_OUT + 16 + r16]);
        }
    }
}

extern "C" void kernel_launch(void* const* d_in, const int* in_sizes, int n_in,
                              void* d_out, int out_size, void* d_ws, size_t ws_size,
                              hipStream_t stream) {
    const float* data    = (const float*)d_in[0];   // [N, C_IN] fp32
    const float* weights = (const float*)d_in[1];   // [K, C_IN, C_OUT] fp32
    const int*   neigh   = (const int*)d_in[2];     // [N, K] int32
    float*       out     = (float*)d_out;           // [N, C_OUT] fp32

    __bf16* data_bf = (__bf16*)d_ws;
    __bf16* wpack   = (__bf16*)((char*)d_ws + (size_t)(N_NODES + 1) * C_IN * sizeof(__bf16));

    hipLaunchKernelGGL(convert_data_kernel, dim3((N_NODES * C_IN / 8 + 255) / 256),
                       dim3(256), 0, stream, data, data_bf);
    hipLaunchKernelGGL(pack_weights_kernel, dim3((KDIM * C_IN * C_OUT + 255) / 256),
                       dim3(256), 0, stream, weights, wpack);
    int blocks = (N_NODES + 127) / 128;
    hipLaunchKernelGGL(octconv_main_kernel, dim3(blocks), dim3(256), 0, stream,
                       neigh, data_bf, wpack, out);
}